// Round 1
// baseline (2887.676 us; speedup 1.0000x reference)
//
#include <hip/hip_runtime.h>

#define TT 100
#define DD 100
#define DC 25      // DD/4
#define PP 10
#define BBATCH 256
#define OC 80
#define NW 8       // waves per block (512 threads)

typedef float v2f __attribute__((ext_vector_type(2)));
typedef float v4f __attribute__((ext_vector_type(4)));

static constexpr float FEPS = 1e-6f;

__device__ __forceinline__ int   f2i(float x) { return __builtin_bit_cast(int, x); }
__device__ __forceinline__ float i2f(int x)   { return __builtin_bit_cast(float, x); }

// DPP row_ror:n within 16-lane rows — VALU pipe, no LDS traffic.
// ctrl: 0x120 + n. Rotate-reduce over {1,2,4,8} covers all 16 lanes exactly once.
#define ROR_F(v, ctrl) i2f(__builtin_amdgcn_update_dpp(0, f2i(v), (ctrl), 0xf, 0xf, false))
#define ROR_I(v, ctrl) __builtin_amdgcn_update_dpp(0, (v), (ctrl), 0xf, 0xf, false)

// lane ^ 32 exchange: returns {self-ish, partner-ish}; for commutative combine
// of the two slots this yields the xor-32 result in every lane.
__device__ __forceinline__ v2f xswap32_f(float v) {
#if __has_builtin(__builtin_amdgcn_permlane32_swap)
  auto pr = __builtin_amdgcn_permlane32_swap((unsigned)f2i(v), (unsigned)f2i(v), false, false);
  v2f r; r.x = i2f((int)pr[0]); r.y = i2f((int)pr[1]);
  return r;
#else
  v2f r; r.x = v; r.y = __shfl_xor(v, 32, 64);
  return r;
#endif
}

__device__ __forceinline__ float wave_sum(float v) {
  v += ROR_F(v, 0x121);
  v += ROR_F(v, 0x122);
  v += ROR_F(v, 0x124);
  v += ROR_F(v, 0x128);
  v += i2f(__builtin_amdgcn_ds_swizzle(f2i(v), 0x401f));   // lane ^ 16
  v2f s = xswap32_f(v);                                    // lane ^ 32
  return s.x + s.y;
}

__device__ __forceinline__ float wave_max(float v) {
  v = fmaxf(v, ROR_F(v, 0x121));
  v = fmaxf(v, ROR_F(v, 0x122));
  v = fmaxf(v, ROR_F(v, 0x124));
  v = fmaxf(v, ROR_F(v, 0x128));
  v = fmaxf(v, i2f(__builtin_amdgcn_ds_swizzle(f2i(v), 0x401f)));
  v2f s = xswap32_f(v);
  return fmaxf(s.x, s.y);
}

__device__ __forceinline__ void amax2(float& v, int& i, float ov, int oi) {
  if (ov > v || (ov == v && oi < i)) { v = ov; i = oi; }
}

__device__ __forceinline__ void wave_argmax(float& v, int& idx) {
  amax2(v, idx, ROR_F(v, 0x121), ROR_I(idx, 0x121));
  amax2(v, idx, ROR_F(v, 0x122), ROR_I(idx, 0x122));
  amax2(v, idx, ROR_F(v, 0x124), ROR_I(idx, 0x124));
  amax2(v, idx, ROR_F(v, 0x128), ROR_I(idx, 0x128));
  amax2(v, idx, i2f(__builtin_amdgcn_ds_swizzle(f2i(v), 0x401f)),
        __builtin_amdgcn_ds_swizzle(idx, 0x401f));
#if __has_builtin(__builtin_amdgcn_permlane32_swap)
  {
    auto rv = __builtin_amdgcn_permlane32_swap((unsigned)f2i(v), (unsigned)f2i(v), false, false);
    auto ri = __builtin_amdgcn_permlane32_swap((unsigned)idx, (unsigned)idx, false, false);
    // slots are {self, partner} in some order; argmax-combine is idempotent, so
    // combining both slots is correct regardless of which is self.
    amax2(v, idx, i2f((int)rv[0]), (int)ri[0]);
    amax2(v, idx, i2f((int)rv[1]), (int)ri[1]);
  }
#else
  amax2(v, idx, __shfl_xor(v, 32, 64), __shfl_xor(idx, 32, 64));
#endif
}

// 512 threads = 8 waves/block; 2 blocks/CU (LDS ~76.5KB) -> 16 waves/CU (was 8).
// __launch_bounds__(512,4): force VGPR<=128 so 4 waves/SIMD actually fit.
__global__ __launch_bounds__(512, 4) void match_kernel(
    const float* __restrict__ s1, const float* __restrict__ s2,
    const float* __restrict__ w1, const float* __restrict__ w2,
    const float* __restrict__ w3, const float* __restrict__ w4,
    const float* __restrict__ w5, const float* __restrict__ w6,
    const float* __restrict__ w7, const float* __restrict__ w8,
    float* __restrict__ out)
{
  const int dir  = blockIdx.x & 1;
  const int b    = blockIdx.x >> 1;
  const int doff = dir * DD;
  const int tid  = threadIdx.x;
  const int lane = tid & 63;
  const int wv   = tid >> 6;

  const float* wfull = dir ? w2 : w1;
  const float* wmax  = dir ? w4 : w3;
  const float* wmean = dir ? w6 : w5;
  const float* watt2 = dir ? w8 : w7;   // fwd: max-att (w7); bwd: mean-att (w8)

  // s2 in d-chunked layout: d = 4c+k. j-stride = 16B (b128-able, conflict-free
  // lane-over-j); chunk stride = 101*4 = 404 dwords == 20 mod 32 (2-way free
  // for lane-over-d b32 reads in phase D).
  __shared__ __align__(16) float S2V[DC][TT + 1][4];
  __shared__ __align__(16) float W2SQ[PP][DD];
  __shared__ float N2PI[TT];
  __shared__ float N2WI[TT][11];        // padded: (11j+p)%32 -> 2-way free
  // Wave-private regions (each wave owns rows [wv*4, wv*4+4)): no barriers needed.
  __shared__ __align__(16) float S1R[4 * NW][DD];
  __shared__ __align__(16) float CROW[4 * NW][DD];
  __shared__ float N1PI[4 * NW];
  __shared__ float N1WI[4 * NW][PP];
  __shared__ int   ARGJ[4 * NW];

  // ---- Phase 1: load s2 tile (d-chunked) + maxpool w^2 (block-coop) ----
  for (int idx = tid; idx < TT * DD; idx += 512) {
    int j = idx / DD, d = idx - j * DD;
    S2V[d >> 2][j][d & 3] = s2[(j * BBATCH + b) * (2 * DD) + doff + d];
  }
  for (int idx = tid; idx < PP * DD; idx += 512) {
    int p = idx / DD, d = idx - p * DD;
    float v = wmax[idx];
    W2SQ[p][d] = v * v;
  }
  __syncthreads();

  // ---- Phase 2: s2 norms (plain exact-ish + weighted rsqrt), float4 reads ----
  for (int task = tid; task < TT + TT * PP; task += 512) {
    if (task < TT) {
      int j = task;
      float a = 0.f;
      for (int c = 0; c < DC; ++c) {
        v4f f = *(const v4f*)&S2V[c][j][0];
#pragma unroll
        for (int k = 0; k < 4; ++k) a = fmaf(f[k], f[k], a);
      }
      N2PI[j] = 1.0f / sqrtf(fmaxf(a, FEPS));   // feeds argmax-sensitive cos
    } else {
      int q = task - TT; int j = q / PP, p = q - j * PP;
      float a = 0.f;
      for (int c = 0; c < DC; ++c) {
        v4f f = *(const v4f*)&S2V[c][j][0];
        v4f w = *(const v4f*)&W2SQ[p][4 * c];
#pragma unroll
        for (int k = 0; k < 4; ++k) a = fmaf(f[k] * f[k], w[k], a);
      }
      N2WI[j][p] = rsqrtf(fmaxf(a, FEPS));
    }
  }
  __syncthreads();
  // ---- After this point: ZERO barriers. All remaining LDS state is either
  // read-only (S2V/W2SQ/N2*) or wave-private (S1R/CROW/N1*/ARGJ); same-wave
  // LDS RAW ordering is guaranteed by program order.

  const int  j0   = lane;
  const int  j1   = 64 + lane;
  const bool act1 = (j1 < TT);
  const int  j1c  = act1 ? j1 : (TT - 1);
  const bool actd = (64 + lane) < DD;
  const int  d1   = actd ? (64 + lane) : (DD - 1);
  const int  c0i  = lane >> 2, k0 = lane & 3;      // phase-D d0 = lane
  const int  c1i  = d1 >> 2,   k1 = d1 & 3;        // phase-D d1

  const int sl = wv * 4;

  // ---- 25 row-groups strided over 8 waves; no inter-wave coupling ----
  for (int g = wv; g < 25; g += NW) {
    const int i0 = g * 4;          // rows i0..i0+3, always < 100

    // wave-private S1R staging: 4 rows x 25 float4 chunks = 100 tasks
    for (int q = lane; q < 4 * DC; q += 64) {
      int rr = q / DC, c = q - rr * DC;
      *(v4f*)&S1R[sl + rr][4 * c] =
          *(const v4f*)&s1[((i0 + rr) * BBATCH + b) * (2 * DD) + doff + 4 * c];
    }

    // wave-private s1 norms: 4 rows x (1 plain + 10 weighted) = 44 lane-tasks
    if (lane < 4 * 11) {
      int rr = lane / 11, q = lane - rr * 11;
      if (q == 0) {
        float a = 0.f;
        for (int c = 0; c < DC; ++c) {
          v4f f = *(const v4f*)&S1R[sl + rr][4 * c];
#pragma unroll
          for (int k = 0; k < 4; ++k) a = fmaf(f[k], f[k], a);
        }
        N1PI[sl + rr] = 1.0f / sqrtf(fmaxf(a, FEPS));
      } else {
        int p = q - 1;
        float a = 0.f;
        for (int c = 0; c < DC; ++c) {
          v4f f = *(const v4f*)&S1R[sl + rr][4 * c];
          v4f w = *(const v4f*)&W2SQ[p][4 * c];
#pragma unroll
          for (int k = 0; k < 4; ++k) a = fmaf(f[k] * f[k], w[k], a);
        }
        N1WI[sl + rr][p] = rsqrtf(fmaxf(a, FEPS));
      }
    }

    float rs[4] = {0, 0, 0, 0};
    v2f attp[4] = {{0, 0}, {0, 0}, {0, 0}, {0, 0}};

    // ---- Phase B: packed (j0,j1) main dot pass, b128 LDS reads ----
    v2f dotp[4] = {{0, 0}, {0, 0}, {0, 0}, {0, 0}};
    v2f wap[4][PP];
#pragma unroll
    for (int r = 0; r < 4; ++r)
#pragma unroll
      for (int p = 0; p < PP; ++p) wap[r][p] = (v2f){0.f, 0.f};

    for (int c = 0; c < DC; ++c) {
      v4f s2a4 = *(const v4f*)&S2V[c][j0][0];
      v4f s2b4 = *(const v4f*)&S2V[c][j1c][0];
      v4f wq[PP];
#pragma unroll
      for (int p = 0; p < PP; ++p) wq[p] = *(const v4f*)&W2SQ[p][4 * c];
      v4f s1v[4];
#pragma unroll
      for (int r = 0; r < 4; ++r) s1v[r] = *(const v4f*)&S1R[sl + r][4 * c];
#pragma unroll
      for (int k = 0; k < 4; ++k) {
        v2f s2ab; s2ab.x = s2a4[k]; s2ab.y = s2b4[k];
#pragma unroll
        for (int r = 0; r < 4; ++r) {
          v2f s1xx; s1xx.x = s1v[r][k]; s1xx.y = s1v[r][k];
          v2f ta = s1xx * s2ab;     // v_pk_mul_f32
          dotp[r] += ta;            // v_pk_add_f32 (same rounding as scalar path)
#pragma unroll
          for (int p = 0; p < PP; ++p) {
            v2f wk; wk.x = wq[p][k]; wk.y = wq[p][k];
            wap[r][p] = __builtin_elementwise_fma(ta, wk, wap[r][p]);  // v_pk_fma_f32
          }
        }
      }
    }

    // ---- Phase C: cos rows, rowsum, argmax, maxpool (DPP/permlane reductions) ----
#pragma unroll
    for (int r = 0; r < 4; ++r) {
      float n1pi_r = N1PI[sl + r];
      float c0 = dotp[r].x * (n1pi_r * N2PI[j0]);
      float c1 = dotp[r].y * (n1pi_r * N2PI[j1c]);
      CROW[sl + r][j0] = c0;
      if (act1) CROW[sl + r][j1] = c1;
      rs[r] = wave_sum(c0 + (act1 ? c1 : 0.f));

      float mv = c0; int mi = j0;
      if (act1 && (c1 > mv)) { mv = c1; mi = j1; }
      wave_argmax(mv, mi);
      if (lane == 0) ARGJ[sl + r] = mi;

#pragma unroll
      for (int p = 0; p < PP; ++p) {
        float v0 = wap[r][p].x * N2WI[j0][p];
        float v1 = act1 ? wap[r][p].y * N2WI[j1c][p] : -3.4e38f;
        float m = wave_max(fmaxf(v0, v1));
        if (lane == 0) {
          out[((i0 + r) * BBATCH + b) * OC + 20 + dir * PP + p] = m * N1WI[sl + r][p];
        }
      }
    }

    // ---- Phase D: mean-att accumulation, packed (d0,d1); reads own CROW rows ----
    for (int j = 0; j < TT; ++j) {
      v2f s2ab; s2ab.x = S2V[c0i][j][k0]; s2ab.y = S2V[c1i][j][k1];
#pragma unroll
      for (int r = 0; r < 4; ++r) {
        float cv = CROW[sl + r][j];
        v2f cc; cc.x = cv; cc.y = cv;
        attp[r] = __builtin_elementwise_fma(cc, s2ab, attp[r]);
      }
    }

    // overwrite own CROW rows with att rows (same-wave ordering suffices)
#pragma unroll
    for (int r = 0; r < 4; ++r) {
      float inv = 1.0f / (rs[r] + FEPS);
      CROW[sl + r][lane] = attp[r].x * inv;
      if (actd) CROW[sl + r][64 + lane] = attp[r].y * inv;
    }

    // ---- Phase E: epilogue: 120 tasks = 4 rows x {full, mean-att, att2} x 10 p
    for (int tk = lane; tk < 120; tk += 64) {
      int r = tk / 30;
      int q = tk - r * 30;
      int set = q / PP;
      int p = q - set * PP;
      const float* wrow = (set == 0 ? wfull : (set == 1 ? wmean : watt2)) + p * DD;
      // reference quirk: s2.reshape(-1,D)[argmax] == s2f[0, argmax, :] (fwd only)
      const float* gat = s2 + ARGJ[sl + r] * (2 * DD);
      float num = 0.f, nx = 0.f, ny = 0.f;
      for (int c = 0; c < DC; ++c) {
        v4f x4 = *(const v4f*)&S1R[sl + r][4 * c];
        v4f y4;
        if (set == 0)                     y4 = *(const v4f*)&S2V[c][TT - 1][0];
        else if (set == 1 || dir == 1)    y4 = *(const v4f*)&CROW[sl + r][4 * c];
        else                              y4 = *(const v4f*)&gat[4 * c];
        v4f w4 = *(const v4f*)&wrow[4 * c];
#pragma unroll
        for (int k = 0; k < 4; ++k) {
          float w2v = w4[k] * w4[k];
          num = fmaf(x4[k] * y4[k], w2v, num);
          nx  = fmaf(x4[k] * x4[k], w2v, nx);
          ny  = fmaf(y4[k] * y4[k], w2v, ny);
        }
      }
      float cres = num * rsqrtf(fmaxf(nx, FEPS)) * rsqrtf(fmaxf(ny, FEPS));
      int ch = (set == 0 ? 0 : (set == 1 ? 40 : 60)) + dir * PP + p;
      out[((i0 + r) * BBATCH + b) * OC + ch] = cres;
    }
  }
}

extern "C" void kernel_launch(void* const* d_in, const int* in_sizes, int n_in,
                              void* d_out, int out_size, void* d_ws, size_t ws_size,
                              hipStream_t stream) {
  const float* s1 = (const float*)d_in[0];
  const float* s2 = (const float*)d_in[1];
  match_kernel<<<dim3(512), dim3(512), 0, stream>>>(
      s1, s2,
      (const float*)d_in[2], (const float*)d_in[3],
      (const float*)d_in[4], (const float*)d_in[5],
      (const float*)d_in[6], (const float*)d_in[7],
      (const float*)d_in[8], (const float*)d_in[9],
      (float*)d_out);
}

// Round 2
// 416.764 us; speedup vs baseline: 6.9288x; 6.9288x over previous
//
#include <hip/hip_runtime.h>

#define TT 100
#define DD 100
#define DC 25      // DD/4
#define PP 10
#define BBATCH 256
#define OC 80
#define NW 8       // waves per block (512 threads)

typedef float v2f __attribute__((ext_vector_type(2)));
typedef float v4f __attribute__((ext_vector_type(4)));

static constexpr float FEPS = 1e-6f;

__device__ __forceinline__ int   f2i(float x) { return __builtin_bit_cast(int, x); }
__device__ __forceinline__ float i2f(int x)   { return __builtin_bit_cast(float, x); }

// DPP row_ror:n within 16-lane rows — VALU pipe, no LDS traffic.
// ctrl: 0x120 + n. Rotate-reduce over {1,2,4,8} covers all 16 lanes exactly once.
#define ROR_F(v, ctrl) i2f(__builtin_amdgcn_update_dpp(0, f2i(v), (ctrl), 0xf, 0xf, false))
#define ROR_I(v, ctrl) __builtin_amdgcn_update_dpp(0, (v), (ctrl), 0xf, 0xf, false)

// lane ^ 32 exchange: returns {self-ish, partner-ish}; for commutative combine
// of the two slots this yields the xor-32 result in every lane.
__device__ __forceinline__ v2f xswap32_f(float v) {
#if __has_builtin(__builtin_amdgcn_permlane32_swap)
  auto pr = __builtin_amdgcn_permlane32_swap((unsigned)f2i(v), (unsigned)f2i(v), false, false);
  v2f r; r.x = i2f((int)pr[0]); r.y = i2f((int)pr[1]);
  return r;
#else
  v2f r; r.x = v; r.y = __shfl_xor(v, 32, 64);
  return r;
#endif
}

__device__ __forceinline__ float wave_sum(float v) {
  v += ROR_F(v, 0x121);
  v += ROR_F(v, 0x122);
  v += ROR_F(v, 0x124);
  v += ROR_F(v, 0x128);
  v += i2f(__builtin_amdgcn_ds_swizzle(f2i(v), 0x401f));   // lane ^ 16
  v2f s = xswap32_f(v);                                    // lane ^ 32
  return s.x + s.y;
}

__device__ __forceinline__ float wave_max(float v) {
  v = fmaxf(v, ROR_F(v, 0x121));
  v = fmaxf(v, ROR_F(v, 0x122));
  v = fmaxf(v, ROR_F(v, 0x124));
  v = fmaxf(v, ROR_F(v, 0x128));
  v = fmaxf(v, i2f(__builtin_amdgcn_ds_swizzle(f2i(v), 0x401f)));
  v2f s = xswap32_f(v);
  return fmaxf(s.x, s.y);
}

__device__ __forceinline__ void amax2(float& v, int& i, float ov, int oi) {
  if (ov > v || (ov == v && oi < i)) { v = ov; i = oi; }
}

__device__ __forceinline__ void wave_argmax(float& v, int& idx) {
  amax2(v, idx, ROR_F(v, 0x121), ROR_I(idx, 0x121));
  amax2(v, idx, ROR_F(v, 0x122), ROR_I(idx, 0x122));
  amax2(v, idx, ROR_F(v, 0x124), ROR_I(idx, 0x124));
  amax2(v, idx, ROR_F(v, 0x128), ROR_I(idx, 0x128));
  amax2(v, idx, i2f(__builtin_amdgcn_ds_swizzle(f2i(v), 0x401f)),
        __builtin_amdgcn_ds_swizzle(idx, 0x401f));
#if __has_builtin(__builtin_amdgcn_permlane32_swap)
  {
    auto rv = __builtin_amdgcn_permlane32_swap((unsigned)f2i(v), (unsigned)f2i(v), false, false);
    auto ri = __builtin_amdgcn_permlane32_swap((unsigned)idx, (unsigned)idx, false, false);
    // slots are {self, partner} in some order; argmax-combine is idempotent, so
    // combining both slots is correct regardless of which is self.
    amax2(v, idx, i2f((int)rv[0]), (int)ri[0]);
    amax2(v, idx, i2f((int)rv[1]), (int)ri[1]);
  }
#else
  amax2(v, idx, __shfl_xor(v, 32, 64), __shfl_xor(idx, 32, 64));
#endif
}

// 512 threads = 8 waves/block; 2 blocks/CU (LDS 76.8KB x2 <= 160KB).
// __launch_bounds__(512,2): register cap 256 — do NOT force lower; R1 showed
// (512,4) caps arch VGPRs at 64 and spills the Phase-B accumulators to scratch
// (FETCH 4.4GB, WRITE 8.9GB, 58% HBM peak). This code needs ~120 VGPR -> with
// the natural allocation we still get 4 waves/SIMD (128-VGPR occupancy step).
__global__ __launch_bounds__(512, 2) void match_kernel(
    const float* __restrict__ s1, const float* __restrict__ s2,
    const float* __restrict__ w1, const float* __restrict__ w2,
    const float* __restrict__ w3, const float* __restrict__ w4,
    const float* __restrict__ w5, const float* __restrict__ w6,
    const float* __restrict__ w7, const float* __restrict__ w8,
    float* __restrict__ out)
{
  const int dir  = blockIdx.x & 1;
  const int b    = blockIdx.x >> 1;
  const int doff = dir * DD;
  const int tid  = threadIdx.x;
  const int lane = tid & 63;
  const int wv   = tid >> 6;

  const float* wfull = dir ? w2 : w1;
  const float* wmax  = dir ? w4 : w3;
  const float* wmean = dir ? w6 : w5;
  const float* watt2 = dir ? w8 : w7;   // fwd: max-att (w7); bwd: mean-att (w8)

  // s2 in d-chunked layout: d = 4c+k. j-stride = 16B (b128-able, conflict-free
  // lane-over-j); chunk stride = 101*4 = 404 dwords == 20 mod 32 (2-way free
  // for lane-over-d b32 reads in phase D).
  __shared__ __align__(16) float S2V[DC][TT + 1][4];
  __shared__ __align__(16) float W2SQ[PP][DD];
  __shared__ float N2PI[TT];
  __shared__ float N2WI[TT][11];        // padded: (11j+p)%32 -> 2-way free
  // Wave-private regions (each wave owns rows [wv*4, wv*4+4)): no barriers needed.
  __shared__ __align__(16) float S1R[4 * NW][DD];
  __shared__ __align__(16) float CROW[4 * NW][DD];
  __shared__ float N1PI[4 * NW];
  __shared__ float N1WI[4 * NW][PP];
  __shared__ int   ARGJ[4 * NW];

  // ---- Phase 1: load s2 tile (d-chunked) + maxpool w^2 (block-coop) ----
  for (int idx = tid; idx < TT * DD; idx += 512) {
    int j = idx / DD, d = idx - j * DD;
    S2V[d >> 2][j][d & 3] = s2[(j * BBATCH + b) * (2 * DD) + doff + d];
  }
  for (int idx = tid; idx < PP * DD; idx += 512) {
    int p = idx / DD, d = idx - p * DD;
    float v = wmax[idx];
    W2SQ[p][d] = v * v;
  }
  __syncthreads();

  // ---- Phase 2: s2 norms (plain exact-ish + weighted rsqrt), float4 reads ----
  for (int task = tid; task < TT + TT * PP; task += 512) {
    if (task < TT) {
      int j = task;
      float a = 0.f;
      for (int c = 0; c < DC; ++c) {
        v4f f = *(const v4f*)&S2V[c][j][0];
#pragma unroll
        for (int k = 0; k < 4; ++k) a = fmaf(f[k], f[k], a);
      }
      N2PI[j] = 1.0f / sqrtf(fmaxf(a, FEPS));   // feeds argmax-sensitive cos
    } else {
      int q = task - TT; int j = q / PP, p = q - j * PP;
      float a = 0.f;
      for (int c = 0; c < DC; ++c) {
        v4f f = *(const v4f*)&S2V[c][j][0];
        v4f w = *(const v4f*)&W2SQ[p][4 * c];
#pragma unroll
        for (int k = 0; k < 4; ++k) a = fmaf(f[k] * f[k], w[k], a);
      }
      N2WI[j][p] = rsqrtf(fmaxf(a, FEPS));
    }
  }
  __syncthreads();
  // ---- After this point: ZERO barriers. All remaining LDS state is either
  // read-only (S2V/W2SQ/N2*) or wave-private (S1R/CROW/N1*/ARGJ); same-wave
  // LDS RAW ordering is guaranteed by program order.

  const int  j0   = lane;
  const int  j1   = 64 + lane;
  const bool act1 = (j1 < TT);
  const int  j1c  = act1 ? j1 : (TT - 1);
  const bool actd = (64 + lane) < DD;
  const int  d1   = actd ? (64 + lane) : (DD - 1);
  const int  c0i  = lane >> 2, k0 = lane & 3;      // phase-D d0 = lane
  const int  c1i  = d1 >> 2,   k1 = d1 & 3;        // phase-D d1

  const int sl = wv * 4;

  // ---- 25 row-groups strided over 8 waves; no inter-wave coupling ----
  for (int g = wv; g < 25; g += NW) {
    const int i0 = g * 4;          // rows i0..i0+3, always < 100

    // wave-private S1R staging: 4 rows x 25 float4 chunks = 100 tasks
    for (int q = lane; q < 4 * DC; q += 64) {
      int rr = q / DC, c = q - rr * DC;
      *(v4f*)&S1R[sl + rr][4 * c] =
          *(const v4f*)&s1[((i0 + rr) * BBATCH + b) * (2 * DD) + doff + 4 * c];
    }

    // wave-private s1 norms: 4 rows x (1 plain + 10 weighted) = 44 lane-tasks
    if (lane < 4 * 11) {
      int rr = lane / 11, q = lane - rr * 11;
      if (q == 0) {
        float a = 0.f;
        for (int c = 0; c < DC; ++c) {
          v4f f = *(const v4f*)&S1R[sl + rr][4 * c];
#pragma unroll
          for (int k = 0; k < 4; ++k) a = fmaf(f[k], f[k], a);
        }
        N1PI[sl + rr] = 1.0f / sqrtf(fmaxf(a, FEPS));
      } else {
        int p = q - 1;
        float a = 0.f;
        for (int c = 0; c < DC; ++c) {
          v4f f = *(const v4f*)&S1R[sl + rr][4 * c];
          v4f w = *(const v4f*)&W2SQ[p][4 * c];
#pragma unroll
          for (int k = 0; k < 4; ++k) a = fmaf(f[k] * f[k], w[k], a);
        }
        N1WI[sl + rr][p] = rsqrtf(fmaxf(a, FEPS));
      }
    }

    float rs[4] = {0, 0, 0, 0};
    v2f attp[4] = {{0, 0}, {0, 0}, {0, 0}, {0, 0}};

    // ---- Phase B: packed (j0,j1) main dot pass, b128 LDS reads ----
    v2f dotp[4] = {{0, 0}, {0, 0}, {0, 0}, {0, 0}};
    v2f wap[4][PP];
#pragma unroll
    for (int r = 0; r < 4; ++r)
#pragma unroll
      for (int p = 0; p < PP; ++p) wap[r][p] = (v2f){0.f, 0.f};

    for (int c = 0; c < DC; ++c) {
      v4f s2a4 = *(const v4f*)&S2V[c][j0][0];
      v4f s2b4 = *(const v4f*)&S2V[c][j1c][0];
      v4f wq[PP];
#pragma unroll
      for (int p = 0; p < PP; ++p) wq[p] = *(const v4f*)&W2SQ[p][4 * c];
      v4f s1v[4];
#pragma unroll
      for (int r = 0; r < 4; ++r) s1v[r] = *(const v4f*)&S1R[sl + r][4 * c];
#pragma unroll
      for (int k = 0; k < 4; ++k) {
        v2f s2ab; s2ab.x = s2a4[k]; s2ab.y = s2b4[k];
#pragma unroll
        for (int r = 0; r < 4; ++r) {
          v2f s1xx; s1xx.x = s1v[r][k]; s1xx.y = s1v[r][k];
          v2f ta = s1xx * s2ab;     // v_pk_mul_f32
          dotp[r] += ta;            // v_pk_add_f32 (same rounding as scalar path)
#pragma unroll
          for (int p = 0; p < PP; ++p) {
            v2f wk; wk.x = wq[p][k]; wk.y = wq[p][k];
            wap[r][p] = __builtin_elementwise_fma(ta, wk, wap[r][p]);  // v_pk_fma_f32
          }
        }
      }
    }

    // ---- Phase C: cos rows, rowsum, argmax, maxpool (DPP/permlane reductions) ----
#pragma unroll
    for (int r = 0; r < 4; ++r) {
      float n1pi_r = N1PI[sl + r];
      float c0 = dotp[r].x * (n1pi_r * N2PI[j0]);
      float c1 = dotp[r].y * (n1pi_r * N2PI[j1c]);
      CROW[sl + r][j0] = c0;
      if (act1) CROW[sl + r][j1] = c1;
      rs[r] = wave_sum(c0 + (act1 ? c1 : 0.f));

      float mv = c0; int mi = j0;
      if (act1 && (c1 > mv)) { mv = c1; mi = j1; }
      wave_argmax(mv, mi);
      if (lane == 0) ARGJ[sl + r] = mi;

#pragma unroll
      for (int p = 0; p < PP; ++p) {
        float v0 = wap[r][p].x * N2WI[j0][p];
        float v1 = act1 ? wap[r][p].y * N2WI[j1c][p] : -3.4e38f;
        float m = wave_max(fmaxf(v0, v1));
        if (lane == 0) {
          out[((i0 + r) * BBATCH + b) * OC + 20 + dir * PP + p] = m * N1WI[sl + r][p];
        }
      }
    }

    // ---- Phase D: mean-att accumulation, packed (d0,d1); reads own CROW rows ----
    for (int j = 0; j < TT; ++j) {
      v2f s2ab; s2ab.x = S2V[c0i][j][k0]; s2ab.y = S2V[c1i][j][k1];
#pragma unroll
      for (int r = 0; r < 4; ++r) {
        float cv = CROW[sl + r][j];
        v2f cc; cc.x = cv; cc.y = cv;
        attp[r] = __builtin_elementwise_fma(cc, s2ab, attp[r]);
      }
    }

    // overwrite own CROW rows with att rows (same-wave ordering suffices)
#pragma unroll
    for (int r = 0; r < 4; ++r) {
      float inv = 1.0f / (rs[r] + FEPS);
      CROW[sl + r][lane] = attp[r].x * inv;
      if (actd) CROW[sl + r][64 + lane] = attp[r].y * inv;
    }

    // ---- Phase E: epilogue: 120 tasks = 4 rows x {full, mean-att, att2} x 10 p
    for (int tk = lane; tk < 120; tk += 64) {
      int r = tk / 30;
      int q = tk - r * 30;
      int set = q / PP;
      int p = q - set * PP;
      const float* wrow = (set == 0 ? wfull : (set == 1 ? wmean : watt2)) + p * DD;
      // reference quirk: s2.reshape(-1,D)[argmax] == s2f[0, argmax, :] (fwd only)
      const float* gat = s2 + ARGJ[sl + r] * (2 * DD);
      float num = 0.f, nx = 0.f, ny = 0.f;
      for (int c = 0; c < DC; ++c) {
        v4f x4 = *(const v4f*)&S1R[sl + r][4 * c];
        v4f y4;
        if (set == 0)                     y4 = *(const v4f*)&S2V[c][TT - 1][0];
        else if (set == 1 || dir == 1)    y4 = *(const v4f*)&CROW[sl + r][4 * c];
        else                              y4 = *(const v4f*)&gat[4 * c];
        v4f w4 = *(const v4f*)&wrow[4 * c];
#pragma unroll
        for (int k = 0; k < 4; ++k) {
          float w2v = w4[k] * w4[k];
          num = fmaf(x4[k] * y4[k], w2v, num);
          nx  = fmaf(x4[k] * x4[k], w2v, nx);
          ny  = fmaf(y4[k] * y4[k], w2v, ny);
        }
      }
      float cres = num * rsqrtf(fmaxf(nx, FEPS)) * rsqrtf(fmaxf(ny, FEPS));
      int ch = (set == 0 ? 0 : (set == 1 ? 40 : 60)) + dir * PP + p;
      out[((i0 + r) * BBATCH + b) * OC + ch] = cres;
    }
  }
}

extern "C" void kernel_launch(void* const* d_in, const int* in_sizes, int n_in,
                              void* d_out, int out_size, void* d_ws, size_t ws_size,
                              hipStream_t stream) {
  const float* s1 = (const float*)d_in[0];
  const float* s2 = (const float*)d_in[1];
  match_kernel<<<dim3(512), dim3(512), 0, stream>>>(
      s1, s2,
      (const float*)d_in[2], (const float*)d_in[3],
      (const float*)d_in[4], (const float*)d_in[5],
      (const float*)d_in[6], (const float*)d_in[7],
      (const float*)d_in[8], (const float*)d_in[9],
      (float*)d_out);
}